// Round 14
// baseline (77.774 us; speedup 1.0000x reference)
//
#include <hip/hip_runtime.h>
#include <math.h>

// Problem constants (fixed by reference)
#define BATCH 2
#define SEQ   1024
#define DM    1024   // D_MODEL
#define MMEM  128    // memory slots
#define MEMD  512    // MEM_DIM
#define RELH  512    // REL_HID
#define KVLD  2560   // ld of combined [keys|values|m_part]
#define QLD   1536   // ld of combined [queries|q_part]

typedef _Float16 f16;
typedef __attribute__((ext_vector_type(2))) _Float16 f16x2;
typedef __attribute__((ext_vector_type(4))) _Float16 f16x4;
typedef __attribute__((ext_vector_type(8))) _Float16 f16x8;
typedef __attribute__((ext_vector_type(4))) float    f32x4;

__device__ inline float dot2acc(f16x2 a, f16x2 b, float c) {
#if __has_builtin(__builtin_amdgcn_fdot2)
    return __builtin_amdgcn_fdot2(a, b, c, false);
#else
    return c + (float)a[0] * (float)b[0] + (float)a[1] * (float)b[1];
#endif
}
__device__ inline f16x2 relu2(f16x2 a) {
    f16x2 z = { (_Float16)0.0f, (_Float16)0.0f };
#if __has_builtin(__builtin_elementwise_max)
    return __builtin_elementwise_max(a, z);
#else
    f16x2 r;
    r[0] = a[0] > z[0] ? a[0] : z[0];
    r[1] = a[1] > z[1] ? a[1] : z[1];
    return r;
#endif
}

// async global->LDS, 16B per lane (wave-uniform LDS base + lane*16)
__device__ inline void llds16(const void* gp, void* lp) {
    __builtin_amdgcn_global_load_lds(
        (const __attribute__((address_space(1))) void*)gp,
        (__attribute__((address_space(3))) void*)lp,
        16, 0, 0);
}

__device__ inline void cast8(const float* __restrict__ in, f16* __restrict__ out, int i) {
    const float4* p = (const float4*)in + (size_t)i * 2;
    float4 a = p[0], b = p[1];
    f16x8 v = { (f16)a.x, (f16)a.y, (f16)a.z, (f16)a.w,
                (f16)b.x, (f16)b.y, (f16)b.z, (f16)b.w };
    *(f16x8*)(out + (size_t)i * 8) = v;
}

__device__ inline void tr_tile(float (*t)[65], const float* __restrict__ in,
                               f16* __restrict__ out, int R, int C, int tile) {
    const int tid = threadIdx.x;
    const int ctiles = C >> 6;
    const int r0 = (tile / ctiles) * 64, c0 = (tile % ctiles) * 64;
    #pragma unroll
    for (int i = 0; i < 16; ++i) {
        int idx = tid + 256 * i;
        int r = idx >> 6, c = idx & 63;
        t[c][r] = in[(size_t)(r0 + r) * C + c0 + c];
    }
    __syncthreads();
    #pragma unroll
    for (int i = 0; i < 16; ++i) {
        int idx = tid + 256 * i;
        int ro = idx >> 6, co = idx & 63;
        out[(size_t)(c0 + ro) * R + r0 + co] = (f16)t[ro][co];
    }
}

// ---------------------------------------------------------------------------
// MFMA GEMM core: f16 A/B via global_load_lds; 3-buffer depth-2 prefetch with
// COUNTED vmcnt (T4, R13-verified). BM=128, BN=128, BK=64, 256 thr = 4 waves;
// per wave 8 llds16/stage and 32 MFMA/K-tile.
// Schedule: [wait vmcnt(8) -> stage(kt) landed; stage(kt+1) in flight] ->
//           s_barrier -> issue STAGE(kt+2) into buf[(kt+2)%3] -> MFMA buf[kt%3].
// Hazards: STAGE(kt+2) writes buf[(kt-1)%3]; all waves' reads of it completed
// before barrier(kt) (ds_reads drain pre-MFMA, barrier orders chip-wide).
// Last tile waits vmcnt(0). asm "memory" clobbers fence the frag ds_reads.
// C(f32,opt)/C2(f16,opt) = A @ Bt^T + bias(LOCAL col index).
// LDS: 3 * (16 + 16) KB = 96 KB.
// ---------------------------------------------------------------------------
__device__ __forceinline__ void gemm_core(
    const f16* __restrict__ A, const f16* __restrict__ Bt,
    const float* __restrict__ bias, float* __restrict__ C,
    f16* __restrict__ C2, int K, int ldc, int lda, int ldb,
    int bx, int by, f16* Al, f16* Bl)
{
    constexpr int BM = 128, BN = 128;
    constexpr int MF = BM / 16, NF = BN / 64;
    constexpr int ABUF = BM * 64, BBUF = BN * 64;
    const int tid = threadIdx.x, lane = tid & 63, wid = tid >> 6;
    const size_t row0 = (size_t)by * BM;
    const size_t col0 = (size_t)bx * BN;
    const int lrow = lane >> 3;
    const int lcs  = (lane & 7) ^ lrow;
    const int r15 = lane & 15, l4 = lane >> 4;

    f32x4 acc[MF][NF];
    #pragma unroll
    for (int m = 0; m < MF; ++m)
        #pragma unroll
        for (int n = 0; n < NF; ++n) acc[m][n] = (f32x4){0.f, 0.f, 0.f, 0.f};

    auto STAGE = [&](int buf, int kt) {
        const f16* Ab = A + row0 * lda + (size_t)kt * 64;
        const f16* Bb = Bt + col0 * ldb + (size_t)kt * 64;
        #pragma unroll
        for (int j = 0; j < BM / 32; ++j) {
            const int c = wid * (BM / 32) + j;
            llds16(Ab + (size_t)(c * 8 + lrow) * lda + lcs * 8,
                   Al + buf * ABUF + c * 512);
        }
        #pragma unroll
        for (int j = 0; j < BN / 32; ++j) {
            const int c = wid * (BN / 32) + j;
            llds16(Bb + (size_t)(c * 8 + lrow) * ldb + lcs * 8,
                   Bl + buf * BBUF + c * 512);
        }
    };

    const int nk = K >> 6;   // call sites: nk in {8, 16}
    STAGE(0, 0);
    STAGE(1, 1);

    int cur = 0, stg = 2;
    for (int kt = 0; kt < nk; ++kt) {
        // stage(kt) landed; stage(kt+1) (8 newest loads) may stay in flight
        if (kt + 1 < nk) asm volatile("s_waitcnt vmcnt(8)" ::: "memory");
        else             asm volatile("s_waitcnt vmcnt(0)" ::: "memory");
        asm volatile("s_barrier" ::: "memory");
        if (kt + 2 < nk) {
            STAGE(stg, kt + 2);
            stg = (stg == 2) ? 0 : stg + 1;
        }
        #pragma unroll
        for (int kk = 0; kk < 2; ++kk) {
            f16x8 af[MF], bfr[NF];
            #pragma unroll
            for (int m = 0; m < MF; ++m) {
                const int rowA = m * 16 + r15;
                af[m] = *(const f16x8*)(Al + cur * ABUF + rowA * 64 +
                                        (((kk * 4 + l4) ^ (r15 & 7)) * 8));
            }
            #pragma unroll
            for (int n = 0; n < NF; ++n) {
                const int rowB = wid * (BN / 4) + n * 16 + r15;
                bfr[n] = *(const f16x8*)(Bl + cur * BBUF + rowB * 64 +
                                         (((kk * 4 + l4) ^ (r15 & 7)) * 8));
            }
            #pragma unroll
            for (int m = 0; m < MF; ++m)
                #pragma unroll
                for (int n = 0; n < NF; ++n)
                    acc[m][n] = __builtin_amdgcn_mfma_f32_16x16x32_f16(
                        af[m], bfr[n], acc[m][n], 0, 0, 0);
        }
        cur = (cur == 2) ? 0 : cur + 1;
    }

    // C/D layout: col = lane&15, row = (lane>>4)*4 + j
    const int cr = l4, cc = r15;
    #pragma unroll
    for (int n = 0; n < NF; ++n) {
        const size_t col = col0 + wid * (BN / 4) + n * 16 + cc;
        const float bvv = bias ? bias[(int)(col - col0)] : 0.f;
        #pragma unroll
        for (int m = 0; m < MF; ++m) {
            #pragma unroll
            for (int j = 0; j < 4; ++j) {
                const size_t row = row0 + m * 16 + cr * 4 + j;
                const float v = acc[m][n][j] + bvv;
                if (C)  C[row * ldc + col] = v;
                if (C2) C2[row * ldc + col] = (f16)v;
            }
        }
    }
}

// ---------------------------------------------------------------------------
// L1 prep: all casts + weight transposes. grid 2048 x 256. (R12 verbatim)
// ---------------------------------------------------------------------------
__global__ __launch_bounds__(256) void prep(
    const float* __restrict__ hs, const float* __restrict__ mem,
    const float* __restrict__ Wq, const float* __restrict__ Wo,
    const float* __restrict__ Wk, const float* __restrict__ Wv,
    const float* __restrict__ W1,
    f16* __restrict__ hs_f16, f16* __restrict__ mem_f16,
    f16* __restrict__ Wq_t, f16* __restrict__ Wo_t,
    f16* __restrict__ btcomb, f16* __restrict__ W1q_t)
{
    __shared__ float t[64][65];
    const int bid = blockIdx.x, tid = threadIdx.x;

    if (bid < 1024) {
        cast8(hs, hs_f16, bid * 256 + tid);
    } else if (bid < 1088) {
        cast8(mem, mem_f16, (bid - 1024) * 256 + tid);
    } else if (bid < 1344) {
        tr_tile(t, Wq, Wq_t, 1024, 1024, bid - 1088);
    } else if (bid < 1600) {
        tr_tile(t, Wo, Wo_t, 1024, 1024, bid - 1344);
    } else if (bid < 1728) {
        tr_tile(t, Wk, btcomb, 512, 1024, bid - 1600);
    } else if (bid < 1856) {
        tr_tile(t, Wv, btcomb + (size_t)1024 * 512, 512, 1024, bid - 1728);
    } else if (bid < 1920) {
        tr_tile(t, W1 + (size_t)1024 * 512, btcomb + (size_t)2048 * 512,
                512, 512, bid - 1856);
    } else {
        tr_tile(t, W1, W1q_t, 1024, 512, bid - 1920);
    }
}

// ---------------------------------------------------------------------------
// L2 gemmA: queries (128 tiles) + kvm (40 tiles). grid 168 x 256. 1 blk/CU.
//   queries: qcat cols [0,1024) = hs_f16 @ Wq_t^T + bq
//   kvm:     [keys|values+bv|m_part+b1] = mem_f16 @ btcomb^T + [bk|bv|b1]
// ---------------------------------------------------------------------------
__global__ __launch_bounds__(256) void gemmA(
    const f16* __restrict__ hs_f16, const f16* __restrict__ Wq_t,
    const float* __restrict__ bq, f16* __restrict__ qcat,
    const f16* __restrict__ mem_f16, const f16* __restrict__ btcomb,
    const float* __restrict__ bk, const float* __restrict__ bv,
    const float* __restrict__ b1, f16* __restrict__ kvm)
{
    __shared__ __align__(16) char smem[98304];   // Al 48 KB | Bl 48 KB
    f16* Al = (f16*)smem;
    f16* Bl = (f16*)(smem + 49152);
    const int bid = blockIdx.x;

    if (bid < 128) {
        const int bx = bid & 7, by = bid >> 3;    // 8 bx x 16 by
        gemm_core(hs_f16, Wq_t, bq + bx * 128, nullptr, qcat,
                  DM, QLD, DM, DM, bx, by, Al, Bl);
    } else {
        const int i = bid - 128;                  // 20 bx x 2 by
        const int bx = i % 20, by = i / 20;
        const float* bseg = (bx < 8)  ? (bk + bx * 128)
                          : (bx < 16) ? (bv + (bx * 128 - 1024))
                                      : (b1 + (bx * 128 - 2048));
        gemm_core(mem_f16, btcomb, bseg, nullptr, kvm,
                  MEMD, KVLD, MEMD, MEMD, bx, by, Al, Bl);
    }
}

// ---------------------------------------------------------------------------
// L3 gemmB: q_part (64 tiles) + VoT (16) + mpt (8). grid 88 x 256.
// ---------------------------------------------------------------------------
__global__ __launch_bounds__(256) void gemmB(
    const f16* __restrict__ qcat_in, f16* __restrict__ qcat,
    const f16* __restrict__ W1q_t, const f16* __restrict__ kvm,
    const f16* __restrict__ Wo_t, f16* __restrict__ VoT,
    f16* __restrict__ mpt)
{
    __shared__ __align__(16) char smem[98304];
    f16* Al = (f16*)smem;
    f16* Bl = (f16*)(smem + 49152);
    const int bid = blockIdx.x, tid = threadIdx.x;

    if (bid < 64) {
        const int bx = bid & 3, by = bid >> 2;    // 4 bx x 16 by
        gemm_core(qcat_in, W1q_t, nullptr, nullptr, qcat + 1024,
                  DM, QLD, QLD, DM, bx, by, Al, Bl);
        return;
    }
    if (bid < 80) {
        const int i = bid - 64;                   // 2 bx x 8 by
        gemm_core(Wo_t, kvm + 1024, nullptr, nullptr, VoT,
                  DM, 256, DM, KVLD, i % 2, i / 2, Al, Bl);
        return;
    }
    // mpt: m_part rows (kvm cols 2048..2560) -> [b][256 h2][128 m][2]
    f16 (*t2)[136] = (f16(*)[136])smem;
    const f16* mpart = kvm + 2048;
    const int mb = bid - 80, b = mb >> 2, hc = mb & 3;
    #pragma unroll
    for (int k = 0; k < 8; ++k) {
        int idx = tid + 256 * k;
        int m = idx >> 4, hq = idx & 15;
        *(f16x8*)(&t2[m][hq * 8]) =
            *(const f16x8*)(mpart + (size_t)(b * 128 + m) * KVLD + hc * 128 + hq * 8);
    }
    __syncthreads();
    #pragma unroll
    for (int k = 0; k < 32; ++k) {
        int idx = tid + 256 * k;
        int h2l = idx >> 7, m = idx & 127;
        f16x2 v = { t2[m][h2l * 2], t2[m][h2l * 2 + 1] };
        *(f16x2*)(mpt + ((size_t)b * 256 + hc * 64 + h2l) * 256 + m * 2) = v;
    }
}

// ---------------------------------------------------------------------------
// L4: fused relevance + scores + softmax + P@Vo + bo -> out (f32).
// grid 256 x 256 (8 s-rows/block). Verbatim from R8/R12/R13 (passing).
// ---------------------------------------------------------------------------
__global__ __launch_bounds__(256) void relattn(
    const f16* __restrict__ qcat,    // [2048][QLD]: queries | q_part
    const f16* __restrict__ kvm,     // [256][KVLD]: keys in cols [0,1024)
    const f16* __restrict__ VoT,     // [1024][256]
    const f16* __restrict__ mpt,     // [b][256 h2][128 m][2]
    const float* __restrict__ W2,    // [512]
    const float* __restrict__ b2,    // [1]
    const float* __restrict__ bo,    // [1024]
    float* __restrict__ out,         // [2048][1024] f32
    float* __restrict__ attn_w)      // [2048][128]
{
    __shared__ __align__(16) char u[41984];      // qs|mps|w2s  then  sc
    __shared__ float rel_s[1024];                // [8][128] persistent
    __shared__ f16 Ps[8 * 136];

    const int tid = threadIdx.x;
    const int b = blockIdx.x >> 7, st = blockIdx.x & 127;
    const size_t rowbase = (size_t)b * SEQ + st * 8;
    const int w = tid >> 6, lane = tid & 63;
    const int l15 = lane & 15, l4 = lane >> 4;

    // ---------------- Phase R: relevance -> rel_s ----------------
    {
        f16* qs  = (f16*)u;                 // [8][512]  8 KB
        f16* mps = (f16*)(u + 8192);        // [64][256] 32 KB
        f16* w2s = (f16*)(u + 40960);       // [512]     1 KB

        {
            int r = tid >> 5, c = tid & 31;
            const f16* src = qcat + (rowbase + r) * QLD + 1024 + c * 16;
            *(f16x8*)(qs + r * 512 + c * 16)     = *(const f16x8*)(src);
            *(f16x8*)(qs + r * 512 + c * 16 + 8) = *(const f16x8*)(src + 8);
        }
        if (tid < 128) {
            float4 w4 = *(const float4*)(W2 + tid * 4);
            f16x4 hv = { (f16)w4.x, (f16)w4.y, (f16)w4.z, (f16)w4.w };
            *(f16x4*)(w2s + tid * 4) = hv;
        }
        const float b2v = b2[0];
        const int sg = w;

        float acc00 = 0.f, acc01 = 0.f, acc10 = 0.f, acc11 = 0.f;
        const f16* mptb = mpt + (size_t)b * 65536;

        for (int hc = 0; hc < 4; ++hc) {
            __syncthreads();
            {
                const f16x8* src = (const f16x8*)(mptb + hc * 16384);
                f16x8* dst = (f16x8*)mps;
                #pragma unroll
                for (int k = 0; k < 8; ++k) dst[tid + 256 * k] = src[tid + 256 * k];
            }
            __syncthreads();

            #pragma unroll 4
            for (int step = 0; step < 16; ++step) {
                const int habs = hc * 128 + step * 8;
                uint4 q0u = *(const uint4*)(qs + (2 * sg) * 512 + habs);
                uint4 q1u = *(const uint4*)(qs + (2 * sg + 1) * 512 + habs);
                uint4 wu  = *(const uint4*)(w2s + habs);
                const unsigned* q0p = (const unsigned*)&q0u;
                const unsigned* q1p = (const unsigned*)&q1u;
                const unsigned* wp_ = (const unsigned*)&wu;
                #pragma unroll
                for (int jj = 0; jj < 4; ++jj) {
                    uint2 mpu = *(const uint2*)(mps + ((step * 4 + jj) * 128 + 2 * lane) * 2);
                    f16x2 m0 = __builtin_bit_cast(f16x2, mpu.x);
                    f16x2 m1 = __builtin_bit_cast(f16x2, mpu.y);
                    f16x2 wp = __builtin_bit_cast(f16x2, wp_[jj]);
                    f16x2 q0 = __builtin_bit_cast(f16x2, q0p[jj]);
                    f16x2 q1 = __builtin_bit_cast(f16x2, q1p[jj]);
                    acc00 = dot2acc(relu2(q0 + m0), wp, acc00);
                    acc01 = dot2acc(relu2(q0 + m1), wp, acc01);
                    acc10 = dot2acc(relu2(q1 + m0), wp, acc10);
                    acc11 = dot2acc(relu2(q1 + m1), wp, acc11);
                }
            }
        }

        rel_s[(2 * sg) * 128 + 2 * lane]         = 1.f / (1.f + __expf(-(acc00 + b2v)));
        rel_s[(2 * sg) * 128 + 2 * lane + 1]     = 1.f / (1.f + __expf(-(acc01 + b2v)));
        rel_s[(2 * sg + 1) * 128 + 2 * lane]     = 1.f / (1.f + __expf(-(acc10 + b2v)));
        rel_s[(2 * sg + 1) * 128 + 2 * lane + 1] = 1.f / (1.f + __expf(-(acc11 + b2v)));
    }
    __syncthreads();   // rel_s ready; qs/mps dead -> sc may overwrite

    float* sc = (float*)u;   // [4][16][128] 32 KB

    // ---------------- Phase S: QK^T partials over k-quarter ----------------
    {
        f32x4 aq[8];
        #pragma unroll
        for (int n = 0; n < 8; ++n) aq[n] = (f32x4){0.f, 0.f, 0.f, 0.f};
        #pragma unroll
        for (int k4 = 0; k4 < 8; ++k4) {
            const int k0 = w * 256 + k4 * 32 + l4 * 8;
            f16x8 af = *(const f16x8*)(qcat + (rowbase + (l15 & 7)) * QLD + k0);
            #pragma unroll
            for (int n = 0; n < 8; ++n) {
                f16x8 bf = *(const f16x8*)(kvm + (size_t)(b * 128 + n * 16 + l15) * KVLD + k0);
                aq[n] = __builtin_amdgcn_mfma_f32_16x16x32_f16(af, bf, aq[n], 0, 0, 0);
            }
        }
        #pragma unroll
        for (int n = 0; n < 8; ++n)
            #pragma unroll
            for (int j = 0; j < 4; ++j)
                sc[(w * 16 + l4 * 4 + j) * 128 + n * 16 + l15] = aq[n][j];
    }
    __syncthreads();

    // ---------------- reduce partials, *rel/32, softmax ----------------
    {
        const int r = tid >> 5, seg = tid & 31;
        float4 xs = {0.f, 0.f, 0.f, 0.f};
        #pragma unroll
        for (int ww = 0; ww < 4; ++ww) {
            float4 p = *(const float4*)(sc + (ww * 16 + r) * 128 + seg * 4);
            xs.x += p.x; xs.y += p.y; xs.z += p.z; xs.w += p.w;
        }
        float4 rl = *(const float4*)(rel_s + r * 128 + seg * 4);
        float x[4];
        x[0] = xs.x * 0.03125f * rl.x; x[1] = xs.y * 0.03125f * rl.y;
        x[2] = xs.z * 0.03125f * rl.z; x[3] = xs.w * 0.03125f * rl.w;
        float mx = fmaxf(fmaxf(x[0], x[1]), fmaxf(x[2], x[3]));
        #pragma unroll
        for (int d = 1; d < 32; d <<= 1) mx = fmaxf(mx, __shfl_xor(mx, d));
        float ss = 0.f;
        #pragma unroll
        for (int c = 0; c < 4; ++c) { x[c] = __expf(x[c] - mx); ss += x[c]; }
        #pragma unroll
        for (int d = 1; d < 32; d <<= 1) ss += __shfl_xor(ss, d);
        const float inv = 1.f / ss;
        #pragma unroll
        for (int c = 0; c < 4; ++c) x[c] *= inv;
        float4 o = { x[0], x[1], x[2], x[3] };
        *(float4*)(attn_w + (rowbase + r) * 128 + seg * 4) = o;
        f16x4 ph = { (f16)x[0], (f16)x[1], (f16)x[2], (f16)x[3] };
        *(f16x4*)(Ps + r * 136 + seg * 4) = ph;
    }
    __syncthreads();

    // ---------------- Phase P: out = P @ Vo + bo over d-quarter ----------------
    {
        f16x8 pa[4];
        #pragma unroll
        for (int k = 0; k < 4; ++k)
            pa[k] = *(const f16x8*)(Ps + (l15 & 7) * 136 + k * 32 + l4 * 8);
        #pragma unroll
        for (int n2 = 0; n2 < 16; ++n2) {
            f32x4 ac = (f32x4){0.f, 0.f, 0.f, 0.f};
            const int d0 = w * 256 + n2 * 16;
            #pragma unroll
            for (int k = 0; k < 4; ++k) {
                f16x8 bf = *(const f16x8*)(VoT + (size_t)(d0 + l15) * 256 + b * 128 + k * 32 + l4 * 8);
                ac = __builtin_amdgcn_mfma_f32_16x16x32_f16(pa[k], bf, ac, 0, 0, 0);
            }
            if (l4 < 2) {
                const float bov = bo[d0 + l15];
                #pragma unroll
                for (int j = 0; j < 4; ++j)
                    out[(rowbase + l4 * 4 + j) * 1024 + d0 + l15] = ac[j] + bov;
            }
        }
    }
}

// ---------------------------------------------------------------------------
extern "C" void kernel_launch(void* const* d_in, const int* in_sizes, int n_in,
                              void* d_out, int out_size, void* d_ws, size_t ws_size,
                              hipStream_t stream)
{
    const float* hs  = (const float*)d_in[0];
    const float* mem = (const float*)d_in[1];
    const float* Wq  = (const float*)d_in[2];
    const float* bq  = (const float*)d_in[3];
    const float* Wk  = (const float*)d_in[4];
    const float* bk  = (const float*)d_in[5];
    const float* Wv  = (const float*)d_in[6];
    const float* bv  = (const float*)d_in[7];
    const float* Wo  = (const float*)d_in[8];
    const float* bo  = (const float*)d_in[9];
    const float* W1  = (const float*)d_in[10];  // (1536,512)
    const float* b1  = (const float*)d_in[11];
    const float* W2  = (const float*)d_in[12];
    const float* b2  = (const float*)d_in[13];

    float* out   = (float*)d_out;                       // (2,1024,1024)
    float* attnw = out + (size_t)BATCH * SEQ * DM;      // (2,1024,128)

    // workspace layout (16B-aligned, ~19.8 MB)
    char* wp = (char*)d_ws;
    f16* hs_f16  = (f16*)wp;  wp += (size_t)BATCH * SEQ * DM * 2;     // 4 MB
    f16* mem_f16 = (f16*)wp;  wp += (size_t)BATCH * MMEM * MEMD * 2;  // 0.25 MB
    f16* Wq_t    = (f16*)wp;  wp += (size_t)DM * DM * 2;              // 2 MB
    f16* Wo_t    = (f16*)wp;  wp += (size_t)DM * DM * 2;              // 2 MB
    f16* btcomb  = (f16*)wp;  wp += (size_t)KVLD * MEMD * 2;          // 2.5 MB
    f16* W1q_t   = (f16*)wp;  wp += (size_t)RELH * DM * 2;            // 1 MB
    f16* qcat    = (f16*)wp;  wp += (size_t)BATCH * SEQ * QLD * 2;    // 6 MB
    f16* kvm     = (f16*)wp;  wp += (size_t)BATCH * MMEM * KVLD * 2;  // 1.25 MB
    f16* VoT     = (f16*)wp;  wp += (size_t)DM * BATCH * MMEM * 2;    // 0.5 MB
    f16* mpt     = (f16*)wp;  wp += (size_t)BATCH * MMEM * RELH * 2;  // 0.25 MB

    dim3 blk(256);

    // L1: casts + weight transposes
    prep<<<dim3(2048), blk, 0, stream>>>(
        hs, mem, Wq, Wo, Wk, Wv, W1,
        hs_f16, mem_f16, Wq_t, Wo_t, btcomb, W1q_t);

    // L2: queries GEMM + kvm GEMM (128x128 tiles, 1 block/CU)
    gemmA<<<dim3(168), blk, 0, stream>>>(
        hs_f16, Wq_t, bq, qcat, mem_f16, btcomb, bk, bv, b1, kvm);

    // L3: q_part GEMM + VoT GEMM + mpt
    gemmB<<<dim3(88), blk, 0, stream>>>(
        qcat, qcat, W1q_t, kvm, Wo_t, VoT, mpt);

    // L4: fused relevance + attention -> out, attn_w
    relattn<<<dim3(256), blk, 0, stream>>>(
        qcat, kvm, VoT, mpt, W2, b2, bo, out, attnw);
}

// Round 15
// 67.838 us; speedup vs baseline: 1.1465x; 1.1465x over previous
//
#include <hip/hip_runtime.h>
#include <math.h>

// Problem constants (fixed by reference)
#define BATCH 2
#define SEQ   1024
#define DM    1024   // D_MODEL
#define MMEM  128    // memory slots
#define MEMD  512    // MEM_DIM
#define RELH  512    // REL_HID
#define KVLD  2560   // ld of combined [keys|values|m_part]
#define QLD   1536   // ld of combined [queries|q_part]

typedef _Float16 f16;
typedef __attribute__((ext_vector_type(2))) _Float16 f16x2;
typedef __attribute__((ext_vector_type(4))) _Float16 f16x4;
typedef __attribute__((ext_vector_type(8))) _Float16 f16x8;
typedef __attribute__((ext_vector_type(4))) float    f32x4;

__device__ inline float dot2acc(f16x2 a, f16x2 b, float c) {
#if __has_builtin(__builtin_amdgcn_fdot2)
    return __builtin_amdgcn_fdot2(a, b, c, false);
#else
    return c + (float)a[0] * (float)b[0] + (float)a[1] * (float)b[1];
#endif
}
__device__ inline f16x2 relu2(f16x2 a) {
    f16x2 z = { (_Float16)0.0f, (_Float16)0.0f };
#if __has_builtin(__builtin_elementwise_max)
    return __builtin_elementwise_max(a, z);
#else
    f16x2 r;
    r[0] = a[0] > z[0] ? a[0] : z[0];
    r[1] = a[1] > z[1] ? a[1] : z[1];
    return r;
#endif
}

// async global->LDS, 16B per lane (wave-uniform LDS base + lane*16)
__device__ inline void llds16(const void* gp, void* lp) {
    __builtin_amdgcn_global_load_lds(
        (const __attribute__((address_space(1))) void*)gp,
        (__attribute__((address_space(3))) void*)lp,
        16, 0, 0);
}

__device__ inline void cast8(const float* __restrict__ in, f16* __restrict__ out, int i) {
    const float4* p = (const float4*)in + (size_t)i * 2;
    float4 a = p[0], b = p[1];
    f16x8 v = { (f16)a.x, (f16)a.y, (f16)a.z, (f16)a.w,
                (f16)b.x, (f16)b.y, (f16)b.z, (f16)b.w };
    *(f16x8*)(out + (size_t)i * 8) = v;
}

__device__ inline void tr_tile(float (*t)[65], const float* __restrict__ in,
                               f16* __restrict__ out, int R, int C, int tile) {
    const int tid = threadIdx.x;
    const int ctiles = C >> 6;
    const int r0 = (tile / ctiles) * 64, c0 = (tile % ctiles) * 64;
    #pragma unroll
    for (int i = 0; i < 16; ++i) {
        int idx = tid + 256 * i;
        int r = idx >> 6, c = idx & 63;
        t[c][r] = in[(size_t)(r0 + r) * C + c0 + c];
    }
    __syncthreads();
    #pragma unroll
    for (int i = 0; i < 16; ++i) {
        int idx = tid + 256 * i;
        int ro = idx >> 6, co = idx & 63;
        out[(size_t)(c0 + ro) * R + r0 + co] = (f16)t[ro][co];
    }
}

// ---------------------------------------------------------------------------
// MFMA GEMM core (R13 verbatim — proven 68.8 µs config):
// f16 A/B via global_load_lds; 3-buffer depth-2 prefetch, counted vmcnt (T4).
// BM=64, BN=128, BK=64, 256 thr = 4 waves, LDS 72 KB.
// ---------------------------------------------------------------------------
__device__ __forceinline__ void gemm_core(
    const f16* __restrict__ A, const f16* __restrict__ Bt,
    const float* __restrict__ bias, float* __restrict__ C,
    f16* __restrict__ C2, int K, int ldc, int lda, int ldb,
    int bx, int by, f16* Al, f16* Bl)
{
    constexpr int BM = 64, BN = 128;
    constexpr int MF = BM / 16, NF = BN / 64;
    constexpr int ABUF = BM * 64, BBUF = BN * 64;
    const int tid = threadIdx.x, lane = tid & 63, wid = tid >> 6;
    const size_t row0 = (size_t)by * BM;
    const size_t col0 = (size_t)bx * BN;
    const int lrow = lane >> 3;
    const int lcs  = (lane & 7) ^ lrow;
    const int r15 = lane & 15, l4 = lane >> 4;

    f32x4 acc[MF][NF];
    #pragma unroll
    for (int m = 0; m < MF; ++m)
        #pragma unroll
        for (int n = 0; n < NF; ++n) acc[m][n] = (f32x4){0.f, 0.f, 0.f, 0.f};

    auto STAGE = [&](int buf, int kt) {
        const f16* Ab = A + row0 * lda + (size_t)kt * 64;
        const f16* Bb = Bt + col0 * ldb + (size_t)kt * 64;
        #pragma unroll
        for (int j = 0; j < BM / 32; ++j) {
            const int c = wid * (BM / 32) + j;
            llds16(Ab + (size_t)(c * 8 + lrow) * lda + lcs * 8,
                   Al + buf * ABUF + c * 512);
        }
        #pragma unroll
        for (int j = 0; j < BN / 32; ++j) {
            const int c = wid * (BN / 32) + j;
            llds16(Bb + (size_t)(c * 8 + lrow) * ldb + lcs * 8,
                   Bl + buf * BBUF + c * 512);
        }
    };

    const int nk = K >> 6;   // all call sites: nk in {8, 16}
    STAGE(0, 0);
    STAGE(1, 1);

    int cur = 0, stg = 2;
    for (int kt = 0; kt < nk; ++kt) {
        if (kt + 1 < nk) asm volatile("s_waitcnt vmcnt(6)" ::: "memory");
        else             asm volatile("s_waitcnt vmcnt(0)" ::: "memory");
        asm volatile("s_barrier" ::: "memory");
        if (kt + 2 < nk) {
            STAGE(stg, kt + 2);
            stg = (stg == 2) ? 0 : stg + 1;
        }
        #pragma unroll
        for (int kk = 0; kk < 2; ++kk) {
            f16x8 af[MF], bfr[NF];
            #pragma unroll
            for (int m = 0; m < MF; ++m) {
                const int rowA = m * 16 + r15;
                af[m] = *(const f16x8*)(Al + cur * ABUF + rowA * 64 +
                                        (((kk * 4 + l4) ^ (r15 & 7)) * 8));
            }
            #pragma unroll
            for (int n = 0; n < NF; ++n) {
                const int rowB = wid * (BN / 4) + n * 16 + r15;
                bfr[n] = *(const f16x8*)(Bl + cur * BBUF + rowB * 64 +
                                         (((kk * 4 + l4) ^ (r15 & 7)) * 8));
            }
            #pragma unroll
            for (int m = 0; m < MF; ++m)
                #pragma unroll
                for (int n = 0; n < NF; ++n)
                    acc[m][n] = __builtin_amdgcn_mfma_f32_16x16x32_f16(
                        af[m], bfr[n], acc[m][n], 0, 0, 0);
        }
        cur = (cur == 2) ? 0 : cur + 1;
    }

    // C/D layout: col = lane&15, row = (lane>>4)*4 + j
    const int cr = l4, cc = r15;
    #pragma unroll
    for (int n = 0; n < NF; ++n) {
        const size_t col = col0 + wid * (BN / 4) + n * 16 + cc;
        const float bvv = bias ? bias[(int)(col - col0)] : 0.f;
        #pragma unroll
        for (int m = 0; m < MF; ++m) {
            #pragma unroll
            for (int j = 0; j < 4; ++j) {
                const size_t row = row0 + m * 16 + cr * 4 + j;
                const float v = acc[m][n][j] + bvv;
                if (C)  C[row * ldc + col] = v;
                if (C2) C2[row * ldc + col] = (f16)v;
            }
        }
    }
}

// ---------------------------------------------------------------------------
// L1 prep: all casts + weight transposes. grid 2048 x 256. (R12/R13 verbatim)
// ---------------------------------------------------------------------------
__global__ __launch_bounds__(256) void prep(
    const float* __restrict__ hs, const float* __restrict__ mem,
    const float* __restrict__ Wq, const float* __restrict__ Wo,
    const float* __restrict__ Wk, const float* __restrict__ Wv,
    const float* __restrict__ W1,
    f16* __restrict__ hs_f16, f16* __restrict__ mem_f16,
    f16* __restrict__ Wq_t, f16* __restrict__ Wo_t,
    f16* __restrict__ btcomb, f16* __restrict__ W1q_t)
{
    __shared__ float t[64][65];
    const int bid = blockIdx.x, tid = threadIdx.x;

    if (bid < 1024) {
        cast8(hs, hs_f16, bid * 256 + tid);
    } else if (bid < 1088) {
        cast8(mem, mem_f16, (bid - 1024) * 256 + tid);
    } else if (bid < 1344) {
        tr_tile(t, Wq, Wq_t, 1024, 1024, bid - 1088);
    } else if (bid < 1600) {
        tr_tile(t, Wo, Wo_t, 1024, 1024, bid - 1344);
    } else if (bid < 1728) {
        tr_tile(t, Wk, btcomb, 512, 1024, bid - 1600);
    } else if (bid < 1856) {
        tr_tile(t, Wv, btcomb + (size_t)1024 * 512, 512, 1024, bid - 1728);
    } else if (bid < 1920) {
        tr_tile(t, W1 + (size_t)1024 * 512, btcomb + (size_t)2048 * 512,
                512, 512, bid - 1856);
    } else {
        tr_tile(t, W1, W1q_t, 1024, 512, bid - 1920);
    }
}

// ---------------------------------------------------------------------------
// L2 gemmA: queries (256 tiles) + kvm (80 tiles). grid 336 x 256. (R13)
// ---------------------------------------------------------------------------
__global__ __launch_bounds__(256) void gemmA(
    const f16* __restrict__ hs_f16, const f16* __restrict__ Wq_t,
    const float* __restrict__ bq, f16* __restrict__ qcat,
    const f16* __restrict__ mem_f16, const f16* __restrict__ btcomb,
    const float* __restrict__ bk, const float* __restrict__ bv,
    const float* __restrict__ b1, f16* __restrict__ kvm)
{
    __shared__ __align__(16) char smem[73728];   // Al 24 KB | Bl 48 KB
    f16* Al = (f16*)smem;
    f16* Bl = (f16*)(smem + 24576);
    const int bid = blockIdx.x;

    if (bid < 256) {
        const int bx = bid & 7, by = bid >> 3;
        gemm_core(hs_f16, Wq_t, bq + bx * 128, nullptr, qcat,
                  DM, QLD, DM, DM, bx, by, Al, Bl);
    } else {
        const int i = bid - 256;            // 20 bx x 4 by
        const int bx = i % 20, by = i / 20;
        const float* bseg = (bx < 8)  ? (bk + bx * 128)
                          : (bx < 16) ? (bv + (bx * 128 - 1024))
                                      : (b1 + (bx * 128 - 2048));
        gemm_core(mem_f16, btcomb, bseg, nullptr, kvm,
                  MEMD, KVLD, MEMD, MEMD, bx, by, Al, Bl);
    }
}

// ---------------------------------------------------------------------------
// L3 gemmB: q_part (128 tiles) + VoT (32) + mpt (8). grid 168 x 256. (R13)
// ---------------------------------------------------------------------------
__global__ __launch_bounds__(256) void gemmB(
    const f16* __restrict__ qcat_in, f16* __restrict__ qcat,
    const f16* __restrict__ W1q_t, const f16* __restrict__ kvm,
    const f16* __restrict__ Wo_t, f16* __restrict__ VoT,
    f16* __restrict__ mpt)
{
    __shared__ __align__(16) char smem[73728];
    f16* Al = (f16*)smem;
    f16* Bl = (f16*)(smem + 24576);
    const int bid = blockIdx.x, tid = threadIdx.x;

    if (bid < 128) {
        const int bx = bid & 3, by = bid >> 2;
        gemm_core(qcat_in, W1q_t, nullptr, nullptr, qcat + 1024,
                  DM, QLD, QLD, DM, bx, by, Al, Bl);
        return;
    }
    if (bid < 160) {
        const int i = bid - 128;
        gemm_core(Wo_t, kvm + 1024, nullptr, nullptr, VoT,
                  DM, 256, DM, KVLD, i % 2, i / 2, Al, Bl);
        return;
    }
    // mpt: m_part rows (kvm cols 2048..2560) -> [b][256 h2][128 m][2]
    f16 (*t2)[136] = (f16(*)[136])smem;
    const f16* mpart = kvm + 2048;
    const int mb = bid - 160, b = mb >> 2, hc = mb & 3;
    #pragma unroll
    for (int k = 0; k < 8; ++k) {
        int idx = tid + 256 * k;
        int m = idx >> 4, hq = idx & 15;
        *(f16x8*)(&t2[m][hq * 8]) =
            *(const f16x8*)(mpart + (size_t)(b * 128 + m) * KVLD + hc * 128 + hq * 8);
    }
    __syncthreads();
    #pragma unroll
    for (int k = 0; k < 32; ++k) {
        int idx = tid + 256 * k;
        int h2l = idx >> 7, m = idx & 127;
        f16x2 v = { t2[m][h2l * 2], t2[m][h2l * 2 + 1] };
        *(f16x2*)(mpt + ((size_t)b * 256 + hc * 64 + h2l) * 256 + m * 2) = v;
    }
}

// ---------------------------------------------------------------------------
// L4: fused relevance + scores + softmax + P@Vo + bo -> out (f32).
// grid 256 x 256 (8 s-rows/block). Phase R widened: b128 m-loads, half-wave
// h-split (jh = lane>>5), final __shfl_xor(.,32) combine. Phases S/softmax/P
// verbatim R13.
// ---------------------------------------------------------------------------
__global__ __launch_bounds__(256) void relattn(
    const f16* __restrict__ qcat,    // [2048][QLD]: queries | q_part
    const f16* __restrict__ kvm,     // [256][KVLD]: keys in cols [0,1024)
    const f16* __restrict__ VoT,     // [1024][256]
    const f16* __restrict__ mpt,     // [b][256 h2][128 m][2]
    const float* __restrict__ W2,    // [512]
    const float* __restrict__ b2,    // [1]
    const float* __restrict__ bo,    // [1024]
    float* __restrict__ out,         // [2048][1024] f32
    float* __restrict__ attn_w)      // [2048][128]
{
    __shared__ __align__(16) char u[41984];      // qs|mps|w2s  then  sc
    __shared__ float rel_s[1024];                // [8][128] persistent
    __shared__ f16 Ps[8 * 136];

    const int tid = threadIdx.x;
    const int b = blockIdx.x >> 7, st = blockIdx.x & 127;
    const size_t rowbase = (size_t)b * SEQ + st * 8;
    const int w = tid >> 6, lane = tid & 63;
    const int l15 = lane & 15, l4 = lane >> 4;

    // ---------------- Phase R: relevance -> rel_s ----------------
    {
        f16* qs  = (f16*)u;                 // [8][512]  8 KB
        f16* mps = (f16*)(u + 8192);        // [64][256] 32 KB
        f16* w2s = (f16*)(u + 40960);       // [512]     1 KB

        {
            int r = tid >> 5, c = tid & 31;
            const f16* src = qcat + (rowbase + r) * QLD + 1024 + c * 16;
            *(f16x8*)(qs + r * 512 + c * 16)     = *(const f16x8*)(src);
            *(f16x8*)(qs + r * 512 + c * 16 + 8) = *(const f16x8*)(src + 8);
        }
        if (tid < 128) {
            float4 w4 = *(const float4*)(W2 + tid * 4);
            f16x4 hv = { (f16)w4.x, (f16)w4.y, (f16)w4.z, (f16)w4.w };
            *(f16x4*)(w2s + tid * 4) = hv;
        }
        const float b2v = b2[0];
        const int sg = w;                // wave -> s-rows 2sg, 2sg+1
        const int jh = lane >> 5;        // half-wave h-slot (0/1)
        const int ml = lane & 31;        // m-group: m = 4*ml .. 4*ml+3

        float a0[4] = {0.f, 0.f, 0.f, 0.f};   // s = 2sg
        float a1[4] = {0.f, 0.f, 0.f, 0.f};   // s = 2sg+1
        const f16* mptb = mpt + (size_t)b * 65536;

        for (int hc = 0; hc < 4; ++hc) {
            __syncthreads();
            {
                const f16x8* src = (const f16x8*)(mptb + hc * 16384);
                f16x8* dst = (f16x8*)mps;
                #pragma unroll
                for (int k = 0; k < 8; ++k) dst[tid + 256 * k] = src[tid + 256 * k];
            }
            __syncthreads();

            #pragma unroll 4
            for (int step = 0; step < 16; ++step) {
                #pragma unroll
                for (int jj2 = 0; jj2 < 2; ++jj2) {
                    const int h2 = step * 4 + jj2 * 2 + jh;     // pair idx [0,64)
                    const int qoff = hc * 128 + h2 * 2;         // f16 idx in row
                    unsigned q0w = *(const unsigned*)(qs + (2 * sg) * 512 + qoff);
                    unsigned q1w = *(const unsigned*)(qs + (2 * sg + 1) * 512 + qoff);
                    unsigned ww  = *(const unsigned*)(w2s + qoff);
                    uint4 mpu = *(const uint4*)(mps + (h2 * 128 + 4 * ml) * 2);
                    f16x2 q0 = __builtin_bit_cast(f16x2, q0w);
                    f16x2 q1 = __builtin_bit_cast(f16x2, q1w);
                    f16x2 wp = __builtin_bit_cast(f16x2, ww);
                    f16x2 mv0 = __builtin_bit_cast(f16x2, mpu.x);
                    f16x2 mv1 = __builtin_bit_cast(f16x2, mpu.y);
                    f16x2 mv2 = __builtin_bit_cast(f16x2, mpu.z);
                    f16x2 mv3 = __builtin_bit_cast(f16x2, mpu.w);
                    a0[0] = dot2acc(relu2(q0 + mv0), wp, a0[0]);
                    a0[1] = dot2acc(relu2(q0 + mv1), wp, a0[1]);
                    a0[2] = dot2acc(relu2(q0 + mv2), wp, a0[2]);
                    a0[3] = dot2acc(relu2(q0 + mv3), wp, a0[3]);
                    a1[0] = dot2acc(relu2(q1 + mv0), wp, a1[0]);
                    a1[1] = dot2acc(relu2(q1 + mv1), wp, a1[1]);
                    a1[2] = dot2acc(relu2(q1 + mv2), wp, a1[2]);
                    a1[3] = dot2acc(relu2(q1 + mv3), wp, a1[3]);
                }
            }
        }

        // combine h-halves across lane^32, sigmoid, write rel_s
        #pragma unroll
        for (int i = 0; i < 4; ++i) {
            a0[i] += __shfl_xor(a0[i], 32);
            a1[i] += __shfl_xor(a1[i], 32);
        }
        if (jh == 0) {
            float4 r0, r1;
            r0.x = 1.f / (1.f + __expf(-(a0[0] + b2v)));
            r0.y = 1.f / (1.f + __expf(-(a0[1] + b2v)));
            r0.z = 1.f / (1.f + __expf(-(a0[2] + b2v)));
            r0.w = 1.f / (1.f + __expf(-(a0[3] + b2v)));
            r1.x = 1.f / (1.f + __expf(-(a1[0] + b2v)));
            r1.y = 1.f / (1.f + __expf(-(a1[1] + b2v)));
            r1.z = 1.f / (1.f + __expf(-(a1[2] + b2v)));
            r1.w = 1.f / (1.f + __expf(-(a1[3] + b2v)));
            *(float4*)(rel_s + (2 * sg) * 128 + 4 * ml)     = r0;
            *(float4*)(rel_s + (2 * sg + 1) * 128 + 4 * ml) = r1;
        }
    }
    __syncthreads();   // rel_s ready; qs/mps dead -> sc may overwrite

    float* sc = (float*)u;   // [4][16][128] 32 KB

    // ---------------- Phase S: QK^T partials over k-quarter ----------------
    {
        f32x4 aq[8];
        #pragma unroll
        for (int n = 0; n < 8; ++n) aq[n] = (f32x4){0.f, 0.f, 0.f, 0.f};
        #pragma unroll
        for (int k4 = 0; k4 < 8; ++k4) {
            const int k0 = w * 256 + k4 * 32 + l4 * 8;
            f16x8 af = *(const f16x8*)(qcat + (rowbase + (l15 & 7)) * QLD + k0);
            #pragma unroll
            for (int n = 0; n < 8; ++n) {
                f16x8 bf = *(const f16x8*)(kvm + (size_t)(b * 128 + n * 16 + l15) * KVLD + k0);
                aq[n] = __builtin_amdgcn_mfma_f32_16x16x32_f16(af, bf, aq[n], 0, 0, 0);
            }
        }
        #pragma unroll
        for (int n = 0; n < 8; ++n)
            #pragma unroll
            for (int j = 0; j < 4; ++j)
                sc[(w * 16 + l4 * 4 + j) * 128 + n * 16 + l15] = aq[n][j];
    }
    __syncthreads();

    // ---------------- reduce partials, *rel/32, softmax ----------------
    {
        const int r = tid >> 5, seg = tid & 31;
        float4 xs = {0.f, 0.f, 0.f, 0.f};
        #pragma unroll
        for (int ww = 0; ww < 4; ++ww) {
            float4 p = *(const float4*)(sc + (ww * 16 + r) * 128 + seg * 4);
            xs.x += p.x; xs.y += p.y; xs.z += p.z; xs.w += p.w;
        }
        float4 rl = *(const float4*)(rel_s + r * 128 + seg * 4);
        float x[4];
        x[0] = xs.x * 0.03125f * rl.x; x[1] = xs.y * 0.03125f * rl.y;
        x[2] = xs.z * 0.03125f * rl.z; x[3] = xs.w * 0.03125f * rl.w;
        float mx = fmaxf(fmaxf(x[0], x[1]), fmaxf(x[2], x[3]));
        #pragma unroll
        for (int d = 1; d < 32; d <<= 1) mx = fmaxf(mx, __shfl_xor(mx, d));
        float ss = 0.f;
        #pragma unroll
        for (int c = 0; c < 4; ++c) { x[c] = __expf(x[c] - mx); ss += x[c]; }
        #pragma unroll
        for (int d = 1; d < 32; d <<= 1) ss += __shfl_xor(ss, d);
        const float inv = 1.f / ss;
        #pragma unroll
        for (int c = 0; c < 4; ++c) x[c] *= inv;
        float4 o = { x[0], x[1], x[2], x[3] };
        *(float4*)(attn_w + (rowbase + r) * 128 + seg * 4) = o;
        f16x4 ph = { (f16)x[0], (f16)x[1], (f16)x[2], (f16)x[3] };
        *(f16x4*)(Ps + r * 136 + seg * 4) = ph;
    }
    __syncthreads();

    // ---------------- Phase P: out = P @ Vo + bo over d-quarter ----------------
    {
        f16x8 pa[4];
        #pragma unroll
        for (int k = 0; k < 4; ++k)
            pa[k] = *(const f16x8*)(Ps + (l15 & 7) * 136 + k * 32 + l4 * 8);
        #pragma unroll
        for (int n2 = 0; n2 < 16; ++n2) {
            f32x4 ac = (f32x4){0.f, 0.f, 0.f, 0.f};
            const int d0 = w * 256 + n2 * 16;
            #pragma unroll
            for (int k = 0; k < 4; ++k) {
                f16x8 bf = *(const f16x8*)(VoT + (size_t)(d0 + l15) * 256 + b * 128 + k * 32 + l4 * 8);
                ac = __builtin_amdgcn_mfma_f32_16x16x32_f16(pa[k], bf, ac, 0, 0, 0);
            }
            if (l4 < 2) {
                const float bov = bo[d0 + l15];
                #pragma unroll
                for (int j = 0; j < 4; ++j)
                    out[(rowbase + l4 * 4 + j) * 1024 + d0 + l15] = ac[j] + bov;
            }
        }
    }
}

// ---------------------------------------------------------------------------
extern "C" void kernel_launch(void* const* d_in, const int* in_sizes, int n_in,
                              void* d_out, int out_size, void* d_ws, size_t ws_size,
                              hipStream_t stream)
{
    const float* hs  = (const float*)d_in[0];
    const float* mem = (const float*)d_in[1];
    const float* Wq  = (const float*)d_in[2];
    const float* bq  = (const float*)d_in[3];
    const float* Wk  = (const float*)d_in[4];
    const float* bk  = (const float*)d_in[5];
    const float* Wv  = (const float*)d_in[6];
    const float* bv  = (const float*)d_in[7];
    const float* Wo  = (const float*)d_in[8];
    const float* bo  = (const float*)d_in[9];
    const float* W1  = (const float*)d_in[10];  // (1536,512)
    const float* b1  = (const float*)d_in[11];
    const float* W2  = (const float*)d_in[12];
    const float* b2  = (const float*)d_in[13];

    float* out   = (float*)d_out;                       // (2,1024,1024)
    float* attnw = out + (size_t)BATCH * SEQ * DM;      // (2,1024,128)

    // workspace layout (16B-aligned, ~19.8 MB)
    char* wp = (char*)d_ws;
    f16* hs_f16  = (f16*)wp;  wp += (size_t)BATCH * SEQ * DM * 2;     // 4 MB
    f16* mem_f16 = (f16*)wp;  wp += (size_t)BATCH * MMEM * MEMD * 2;  // 0.25 MB
    f16* Wq_t    = (f16*)wp;  wp += (size_t)DM * DM * 2;              // 2 MB
    f16* Wo_t    = (f16*)wp;  wp += (size_t)DM * DM * 2;              // 2 MB
    f16* btcomb  = (f16*)wp;  wp += (size_t)KVLD * MEMD * 2;          // 2.5 MB
    f16* W1q_t   = (f16*)wp;  wp += (size_t)RELH * DM * 2;            // 1 MB
    f16* qcat    = (f16*)wp;  wp += (size_t)BATCH * SEQ * QLD * 2;    // 6 MB
    f16* kvm     = (f16*)wp;  wp += (size_t)BATCH * MMEM * KVLD * 2;  // 1.25 MB
    f16* VoT     = (f16*)wp;  wp += (size_t)DM * BATCH * MMEM * 2;    // 0.5 MB
    f16* mpt     = (f16*)wp;  wp += (size_t)BATCH * MMEM * RELH * 2;  // 0.25 MB

    dim3 blk(256);

    // L1: casts + weight transposes
    prep<<<dim3(2048), blk, 0, stream>>>(
        hs, mem, Wq, Wo, Wk, Wv, W1,
        hs_f16, mem_f16, Wq_t, Wo_t, btcomb, W1q_t);

    // L2: queries GEMM + kvm GEMM
    gemmA<<<dim3(336), blk, 0, stream>>>(
        hs_f16, Wq_t, bq, qcat, mem_f16, btcomb, bk, bv, b1, kvm);

    // L3: q_part GEMM + VoT GEMM + mpt
    gemmB<<<dim3(168), blk, 0, stream>>>(
        qcat, qcat, W1q_t, kvm, Wo_t, VoT, mpt);

    // L4: fused relevance + attention -> out, attn_w
    relattn<<<dim3(256), blk, 0, stream>>>(
        qcat, kvm, VoT, mpt, W2, b2, bo, out, attnw);
}